// Round 9
// baseline (210.440 us; speedup 1.0000x reference)
//
#include <hip/hip_runtime.h>
#include <hip/hip_bf16.h>
#include <math.h>

typedef float f32x4 __attribute__((ext_vector_type(4)));
typedef __bf16 bf16x8 __attribute__((ext_vector_type(8)));

#define PI2 6.283185307179586

static __device__ __forceinline__ unsigned short f2b(float f) {
  __hip_bfloat16 h = __float2bfloat16(f);
  return reinterpret_cast<unsigned short&>(h);
}

// ---------------- setup: pos table + Tt + Ub (Ub stored XOR-swizzled) ----------------
__global__ __launch_bounds__(256) void setup_tables_kernel(
    unsigned short* __restrict__ post16, __hip_bfloat16* __restrict__ Tt,
    __hip_bfloat16* __restrict__ Ub) {
  const int tid = threadIdx.x;
  __shared__ int cnt[64];
  __shared__ int pref[64];

  if (tid < 64) {
    int i = tid;
    double ys = -1.0 + (double)i * (2.0 / 63.0);
    int cRow = 0;
    for (int j = 0; j < 33; ++j) {
      double xs = (double)j / 32.0;
      bool m = (fabs(xs) < 0.1) || (fabs(ys) < 0.1) || (xs * xs + ys * ys <= 0.16);
      cRow += m ? 1 : 0;
    }
    cnt[i] = cRow;
  }
  __syncthreads();
  if (tid == 0) {
    int s = 0;
    for (int i = 0; i < 64; ++i) { pref[i] = s; s += cnt[i]; }
  }
  __syncthreads();
  if (tid < 64) {
    int i = tid;
    int k = pref[i];
    double ys = -1.0 + (double)i * (2.0 / 63.0);
    for (int j = 0; j < 36; ++j) {
      unsigned short v = 0xFFFFu;
      if (j < 33) {
        double xs = (double)j / 32.0;
        bool m = (fabs(xs) < 0.1) || (fabs(ys) < 0.1) || (xs * xs + ys * ys <= 0.16);
        if (m) v = (unsigned short)(k++);
      }
      post16[i * 36 + j] = v;
    }
  }

  // Tt[80][64]: rows 0..32 = cos(2*pi*n*w/64), rows 40..72 = -sin, else 0 (linear)
  for (int idx = tid; idx < 80 * 64; idx += 256) {
    int n = idx >> 6, w = idx & 63;
    float v = 0.0f;
    if (n < 33) {
      int r = (n * w) & 63;
      v = cosf((float)(PI2 / 64.0) * (float)r);
    } else if (n >= 40 && n < 73) {
      int r = ((n - 40) * w) & 63;
      v = -sinf((float)(PI2 / 64.0) * (float)r);
    }
    Tt[idx] = __float2bfloat16(v);
  }

  // Ub[128][128]: row u'<64: [cos | sin], row u'>=64: [-sin | cos], v=(u+32)&63.
  // Stored XOR-SWIZZLED: elem (up,kk) at byte up*256 + ((kk>>3)^(up&15))*16 + (kk&7)*2
  for (int idx = tid; idx < 128 * 128; idx += 256) {
    int up = idx >> 7, kk = idx & 127;
    int u = up & 63;
    int vfreq = (u + 32) & 63;
    int h = kk & 63;
    int r = (vfreq * h) & 63;
    float cv, sv;
    __sincosf((float)(PI2 / 64.0) * (float)r, &sv, &cv);
    float val;
    if (up < 64) val = (kk < 64) ? cv : sv;
    else         val = (kk < 64) ? -sv : cv;
    int off = up * 256 + (((kk >> 3) ^ (up & 15)) * 16) + (kk & 7) * 2;
    *reinterpret_cast<unsigned short*>((char*)Ub + off) = f2b(val);
  }
}

// ---------------- weight fp32 -> bf16, K-padded (B^T layout) ----------------
__global__ __launch_bounds__(256) void wconv_kernel(
    const float* __restrict__ W, __hip_bfloat16* __restrict__ wB,
    int N, int Kd, int Kp) {
  int total = N * Kp;
  for (int idx = blockIdx.x * 256 + threadIdx.x; idx < total; idx += gridDim.x * 256) {
    int e = idx / Kp;
    int f = idx - e * Kp;
    float v = (f < Kd) ? W[(size_t)e * Kd + f] : 0.0f;
    wB[idx] = __float2bfloat16(v);
  }
}

// -------- stage 1: row-DFT per image (2 waves/image, 2 images/block) --------
// Phases A/B/C as verified, then RAW coalesced copy-out of the (swizzled)
// Sout buffer -> S2 global. S2's global layout IS the swizzled layout, so
// stage-2's linear DMA into LDS + swizzled ds_read is conflict-free (m173).
__global__ __launch_bounds__(256, 4) void s1_kernel(
    const float* __restrict__ x,
    const __hip_bfloat16* __restrict__ Tt,   // [80][64] linear
    unsigned int* __restrict__ S2) {         // [img][2112 dw] swizzled bf16
  __shared__ __align__(16) char lds[2 * 8704];
  const int tid = threadIdx.x;
  const int lane = tid & 63;
  const int w = tid >> 6;
  const int wi = w >> 1;       // image slot
  const int wp = w & 1;        // row-half
  const int l4 = lane & 15;
  const int q = lane >> 4;
  const int img = blockIdx.x * 2 + wi;
  char* ibuf = lds + wi * 8704;

  // ---- phase A: 8 float4 rows (own half) -> regs -> cvt -> swizzled Xbf
  {
    const float* xi = x + (size_t)img * 4096;
    float4 st[8];
    #pragma unroll
    for (int r = 0; r < 8; ++r) {
      int row = wp * 32 + r * 4 + q;
      st[r] = *reinterpret_cast<const float4*>(xi + row * 64 + l4 * 4);
    }
    #pragma unroll
    for (int r = 0; r < 8; ++r) {
      int row = wp * 32 + r * 4 + q;
      int off = row * 128 + (((l4 >> 1) ^ (row & 7)) * 16 + (l4 & 1) * 8);
      ushort4 b;
      b.x = f2b(st[r].x); b.y = f2b(st[r].y); b.z = f2b(st[r].z); b.w = f2b(st[r].w);
      *reinterpret_cast<ushort4*>(ibuf + off) = b;
    }
  }

  // ---- phase B: S[own 32 rows][80] = X * Tt^T  (20 MFMA)
  f32x4 acc1[2][5] = {};
  #pragma unroll
  for (int ks = 0; ks < 2; ++ks) {
    bf16x8 a1[2], b1[5];
    #pragma unroll
    for (int am = 0; am < 2; ++am) {
      int h = wp * 32 + am * 16 + l4;
      int kg = ks * 4 + q;
      a1[am] = *reinterpret_cast<const bf16x8*>(ibuf + h * 128 + ((kg ^ (h & 7)) * 16));
    }
    #pragma unroll
    for (int n = 0; n < 5; ++n) {
      int row = n * 16 + l4;
      b1[n] = *reinterpret_cast<const bf16x8*>(
          (const char*)Tt + row * 128 + ks * 64 + q * 16);
    }
    #pragma unroll
    for (int am = 0; am < 2; ++am)
      #pragma unroll
      for (int n = 0; n < 5; ++n)
        acc1[am][n] = __builtin_amdgcn_mfma_f32_16x16x32_bf16(a1[am], b1[n], acc1[am][n], 0, 0, 0);
  }

  __syncthreads();   // both waves done reading Xbf (C overlays it)

  // ---- phase C: write Sout[j<33][kk] (Re kk=h, Im kk=64+h), XOR-swizzled, packed
  #pragma unroll
  for (int n = 0; n < 5; ++n) {
    int col = n * 16 + l4;
    bool isRe = (col < 33);
    bool isIm = (col >= 40 && col < 73);
    if (!(isRe || isIm)) continue;
    int j = isRe ? col : (col - 40);
    #pragma unroll
    for (int am = 0; am < 2; ++am) {
      int h0 = wp * 32 + am * 16 + q * 4;
      int kk0 = isRe ? h0 : (h0 + 64);
      int off = j * 256 + (((kk0 >> 3) ^ (j & 15)) * 16 + (kk0 & 7) * 2);
      ushort4 b;
      b.x = f2b(acc1[am][n][0]); b.y = f2b(acc1[am][n][1]);
      b.z = f2b(acc1[am][n][2]); b.w = f2b(acc1[am][n][3]);
      *reinterpret_cast<ushort4*>(ibuf + off) = b;
    }
  }

  __syncthreads();   // Sout complete (both kk halves)

  // ---- copy-out: RAW copy Sout (swizzled, 33 rows) -> S2, fully coalesced
  {
    const int t2 = tid & 127;      // 128 threads per image
    unsigned int* dst = S2 + (size_t)img * 2112;
    const unsigned int* src = reinterpret_cast<const unsigned int*>(ibuf);
    #pragma unroll
    for (int ii = 0; ii < 17; ++ii) {
      int i = ii * 128 + t2;
      if (i < 2112) dst[i] = src[i];
    }
  }
}

// -------- stage 2: C2 = Ub x S2 per image (1 wave/image, 4 images/block) --------
// Both operands staged in LDS via linear global_load_lds (layouts pre-swizzled
// in global), so the 96-MFMA loop is pure conflict-free ds_read_b128.
// LDS: Ub 32768 + post 4608 + 4*8448 (S2) + 4*2176 (featbuf) = 78080 B -> 2 blocks/CU.
#define S2B 8448

__global__ __launch_bounds__(256, 2) void s2_kernel(
    const char* __restrict__ S2,             // [img][33][128] bf16 swizzled
    const __hip_bfloat16* __restrict__ Ub,   // [128][128] bf16 swizzled
    const unsigned short* __restrict__ post16,
    __hip_bfloat16* __restrict__ feats,
    int K, int Kp) {
  __shared__ __align__(16) char lds[32768 + 4608 + 4 * S2B + 4 * 2176];
  const int tid = threadIdx.x;
  const int lane = tid & 63;
  const int w = tid >> 6;
  const int l4 = lane & 15;
  const int q = lane >> 4;
  char* ubl = lds;
  unsigned short* postl = (unsigned short*)(lds + 32768);
  char* s2l = lds + 32768 + 4608 + w * S2B;
  unsigned short* fbs = (unsigned short*)(lds + 32768 + 4608 + 4 * S2B + w * 2176);

  const int img = blockIdx.x * 4 + w;
  const int sp = img / 3;
  const int c = img - sp * 3;
  const char* simg = S2 + (size_t)img * S2B;

  // ---- prologue: Ub (32 chunks of 1KB, 8/wave), own S2 (8x1KB + 256B), post
  #pragma unroll
  for (int i = 0; i < 8; ++i) {
    const char* g = (const char*)Ub + (size_t)(w * 8 + i) * 1024 + lane * 16;
    char* l = ubl + (size_t)(w * 8 + i) * 1024;
    __builtin_amdgcn_global_load_lds(
        (const __attribute__((address_space(1))) void*)g,
        (__attribute__((address_space(3))) void*)l, 16, 0, 0);
  }
  #pragma unroll
  for (int i = 0; i < 8; ++i) {
    const char* g = simg + i * 1024 + lane * 16;
    char* l = s2l + i * 1024;
    __builtin_amdgcn_global_load_lds(
        (const __attribute__((address_space(1))) void*)g,
        (__attribute__((address_space(3))) void*)l, 16, 0, 0);
  }
  {
    const char* g = simg + 8192 + lane * 4;
    char* l = s2l + 8192;
    __builtin_amdgcn_global_load_lds(
        (const __attribute__((address_space(1))) void*)g,
        (__attribute__((address_space(3))) void*)l, 4, 0, 0);
  }
  {
    const unsigned int* src = reinterpret_cast<const unsigned int*>(post16);
    unsigned int* dst = reinterpret_cast<unsigned int*>(postl);
    #pragma unroll
    for (int i = 0; i < 5; ++i) {
      int idx = i * 256 + tid;
      if (idx < 1152) dst[idx] = src[idx];
    }
  }
  asm volatile("s_waitcnt vmcnt(0)" ::: "memory");
  __syncthreads();

  // ---- GEMM: C2[128 u'][48 j] = Ub[128][128] * S2_img[48][128]^T  (96 MFMA)
  // j-rows >32 read in-bounds garbage (next wave's tile / featbuf); outputs discarded.
  f32x4 acc[8][3] = {};
  #pragma unroll
  for (int ks = 0; ks < 4; ++ks) {
    const int kg = ks * 4 + q;
    bf16x8 bfr[3];
    #pragma unroll
    for (int n = 0; n < 3; ++n) {
      int j = n * 16 + l4;
      bfr[n] = *reinterpret_cast<const bf16x8*>(s2l + j * 256 + ((kg ^ (j & 15)) * 16));
    }
    #pragma unroll
    for (int m = 0; m < 8; ++m) {
      int row = m * 16 + l4;
      bf16x8 afr = *reinterpret_cast<const bf16x8*>(
          ubl + row * 256 + ((kg ^ (row & 15)) * 16));
      #pragma unroll
      for (int n = 0; n < 3; ++n)
        acc[m][n] = __builtin_amdgcn_mfma_f32_16x16x32_bf16(afr, bfr[n], acc[m][n], 0, 0, 0);
    }
  }

  // ---- gather epilogue: C[row=u'][col=j] -> featbuf (wave-private, no barrier)
  #pragma unroll
  for (int n = 0; n < 3; ++n) {
    int col = n * 16 + l4;            // j
    if (col > 32) continue;
    #pragma unroll
    for (int m = 0; m < 8; ++m) {
      #pragma unroll
      for (int r = 0; r < 4; ++r) {
        int row = m * 16 + q * 4 + r; // u' 0..127
        int u = row & 63;
        int base = (row >> 6) ? K : 0;
        unsigned short k = postl[u * 36 + col];
        if (k != 0xFFFFu)
          fbs[base + k] = f2b(acc[m][n][r]);
      }
    }
  }

  // ---- copy featbuf -> feats (two contiguous dword runs, 64 lanes) + zero pad
  {
    size_t obase = (size_t)sp * Kp;
    const unsigned int* fb = reinterpret_cast<const unsigned int*>(fbs);
    unsigned int* gRe = reinterpret_cast<unsigned int*>(feats + obase + (size_t)c * K);
    unsigned int* gIm = reinterpret_cast<unsigned int*>(feats + obase + (size_t)3 * K + (size_t)c * K);
    const int KD2 = K / 2;   // 271
    for (int i = lane; i < KD2; i += 64) {
      gRe[i] = fb[i];
      gIm[i] = fb[KD2 + i];
    }
    if (c == 2) {
      unsigned int* gp = reinterpret_cast<unsigned int*>(feats + obase + (size_t)6 * K);
      int padDw = (Kp - 6 * K) / 2;
      if (lane < padDw) gp[lane] = 0u;
    }
  }
}

// ---------------- bf16 MFMA GEMM: out[M][N] = A[M][Kp] * B[N][Kp]^T + bias ----------------
#define BM 128
#define BN 128
#define BKK 64

__global__ __launch_bounds__(256) void gemm_bias_kernel(
    const __hip_bfloat16* __restrict__ A, const __hip_bfloat16* __restrict__ B,
    const float* __restrict__ bias, float* __restrict__ C,
    int M, int N, int Kp) {
  __shared__ __align__(16) unsigned short As[BM * BKK];
  __shared__ __align__(16) unsigned short Bs[BN * BKK];

  const int tid = threadIdx.x;
  const int lane = tid & 63;
  const int wid = tid >> 6;
  const int wm = wid & 1;
  const int wn = wid >> 1;
  const int nbm = M / BM;
  const int bm = blockIdx.x % nbm;
  const int bn = blockIdx.x / nbm;
  const int row0A = bm * BM;
  const int row0B = bn * BN;

  f32x4 acc[4][4] = {};

  for (int k0 = 0; k0 < Kp; k0 += BKK) {
    #pragma unroll
    for (int i = 0; i < 4; ++i) {
      int qc = i * 256 + tid;
      int r = qc >> 3;
      int cb = (qc & 7) * 16;
      const char* gA = (const char*)A + ((size_t)(row0A + r) * Kp + k0) * 2 + cb;
      const char* gB = (const char*)B + ((size_t)(row0B + r) * Kp + k0) * 2 + cb;
      char* lA = (char*)As + (size_t)(i * 256 + wid * 64) * 16;
      char* lB = (char*)Bs + (size_t)(i * 256 + wid * 64) * 16;
      __builtin_amdgcn_global_load_lds((const __attribute__((address_space(1))) void*)gA,
                                       (__attribute__((address_space(3))) void*)lA, 16, 0, 0);
      __builtin_amdgcn_global_load_lds((const __attribute__((address_space(1))) void*)gB,
                                       (__attribute__((address_space(3))) void*)lB, 16, 0, 0);
    }
    __syncthreads();

    #pragma unroll
    for (int kk = 0; kk < 2; ++kk) {
      bf16x8 afr[4], bfr[4];
      const int ke = kk * 32 + (lane >> 4) * 8;
      #pragma unroll
      for (int m = 0; m < 4; ++m) {
        int rowA = wm * 64 + m * 16 + (lane & 15);
        afr[m] = *reinterpret_cast<const bf16x8*>(&As[rowA * BKK + ke]);
      }
      #pragma unroll
      for (int n = 0; n < 4; ++n) {
        int rowB = wn * 64 + n * 16 + (lane & 15);
        bfr[n] = *reinterpret_cast<const bf16x8*>(&Bs[rowB * BKK + ke]);
      }
      #pragma unroll
      for (int m = 0; m < 4; ++m)
        #pragma unroll
        for (int n = 0; n < 4; ++n)
          acc[m][n] = __builtin_amdgcn_mfma_f32_16x16x32_bf16(afr[m], bfr[n], acc[m][n], 0, 0, 0);
    }
    __syncthreads();
  }

  #pragma unroll
  for (int n = 0; n < 4; ++n) {
    int gcol = row0B + wn * 64 + n * 16 + (lane & 15);
    float bv = bias[gcol];
    #pragma unroll
    for (int m = 0; m < 4; ++m) {
      int grow0 = row0A + wm * 64 + m * 16 + (lane >> 4) * 4;
      #pragma unroll
      for (int r = 0; r < 4; ++r) {
        C[(size_t)(grow0 + r) * N + gcol] = acc[m][n][r] + bv;
      }
    }
  }
}

extern "C" void kernel_launch(void* const* d_in, const int* in_sizes, int n_in,
                              void* d_out, int out_size, void* d_ws, size_t ws_size,
                              hipStream_t stream) {
  const float* x = (const float*)d_in[0];
  const float* W = (const float*)d_in[2];
  const float* bias = (const float*)d_in[3];
  float* out = (float*)d_out;

  const int ENC = in_sizes[3];                 // 1024
  const int Kd = in_sizes[2] / ENC;            // 6*K = 3252
  const int K = Kd / 6;                        // 542
  const int NIMG = in_sizes[0] / 4096;         // 12288
  const int SP = NIMG / 3;                     // 4096
  const int Kp = (Kd + 63) & ~63;              // 3264

  char* ws = (char*)d_ws;
  unsigned short* post16 = (unsigned short*)ws;            // 4608 (region 9216)
  __hip_bfloat16* Tt = (__hip_bfloat16*)(ws + 9216);       // 10240
  __hip_bfloat16* Ub = (__hip_bfloat16*)(ws + 19456);      // 32768 (swizzled)
  __hip_bfloat16* wB = (__hip_bfloat16*)(ws + 52224);      // ENC*Kp*2
  size_t wBytes = (size_t)ENC * Kp * 2;
  __hip_bfloat16* feats = (__hip_bfloat16*)(ws + 52224 + wBytes);
  size_t featsBytes = (size_t)SP * Kp * 2;
  char* S2 = ws + 52224 + wBytes + featsBytes;             // NIMG*8448 (+ slack)

  setup_tables_kernel<<<1, 256, 0, stream>>>(post16, Tt, Ub);
  wconv_kernel<<<1024, 256, 0, stream>>>(W, wB, ENC, Kd, Kp);
  s1_kernel<<<NIMG / 2, 256, 0, stream>>>(x, Tt, (unsigned int*)S2);
  s2_kernel<<<NIMG / 4, 256, 0, stream>>>(S2, Ub, post16, feats, K, Kp);
  gemm_bias_kernel<<<(SP / BM) * (ENC / BN), 256, 0, stream>>>(feats, wB, bias, out, SP, ENC, Kp);
}

// Round 12
// 191.550 us; speedup vs baseline: 1.0986x; 1.0986x over previous
//
#include <hip/hip_runtime.h>
#include <hip/hip_bf16.h>
#include <math.h>

typedef float f32x4 __attribute__((ext_vector_type(4)));
typedef __bf16 bf16x8 __attribute__((ext_vector_type(8)));

#define PI2 6.283185307179586

static __device__ __forceinline__ unsigned short f2b(float f) {
  __hip_bfloat16 h = __float2bfloat16(f);
  return reinterpret_cast<unsigned short&>(h);
}

// ---------------- setup: pos table (ushort [64][36]) + twiddle tables ----------------
__global__ __launch_bounds__(256) void setup_tables_kernel(
    unsigned short* __restrict__ post16, __hip_bfloat16* __restrict__ Tt,
    __hip_bfloat16* __restrict__ Ub) {
  const int tid = threadIdx.x;
  __shared__ int cnt[64];
  __shared__ int pref[64];

  if (tid < 64) {
    int i = tid;
    double ys = -1.0 + (double)i * (2.0 / 63.0);
    int cRow = 0;
    for (int j = 0; j < 33; ++j) {
      double xs = (double)j / 32.0;
      bool m = (fabs(xs) < 0.1) || (fabs(ys) < 0.1) || (xs * xs + ys * ys <= 0.16);
      cRow += m ? 1 : 0;
    }
    cnt[i] = cRow;
  }
  __syncthreads();
  if (tid == 0) {
    int s = 0;
    for (int i = 0; i < 64; ++i) { pref[i] = s; s += cnt[i]; }
  }
  __syncthreads();
  if (tid < 64) {
    int i = tid;
    int k = pref[i];
    double ys = -1.0 + (double)i * (2.0 / 63.0);
    for (int j = 0; j < 36; ++j) {
      unsigned short v = 0xFFFFu;
      if (j < 33) {
        double xs = (double)j / 32.0;
        bool m = (fabs(xs) < 0.1) || (fabs(ys) < 0.1) || (xs * xs + ys * ys <= 0.16);
        if (m) v = (unsigned short)(k++);
      }
      post16[i * 36 + j] = v;
    }
  }

  // Tt[80][64]: rows 0..32 = cos(2*pi*n*w/64), rows 40..72 = -sin, else 0
  for (int idx = tid; idx < 80 * 64; idx += 256) {
    int n = idx >> 6, w = idx & 63;
    float v = 0.0f;
    if (n < 33) {
      int r = (n * w) & 63;
      v = cosf((float)(PI2 / 64.0) * (float)r);
    } else if (n >= 40 && n < 73) {
      int r = ((n - 40) * w) & 63;
      v = -sinf((float)(PI2 / 64.0) * (float)r);
    }
    Tt[idx] = __float2bfloat16(v);
  }

  // Ub[128][128]: row u'=u   : [cos | sin], row u'=64+u : [-sin | cos], v=(u+32)&63
  for (int idx = tid; idx < 128 * 128; idx += 256) {
    int up = idx >> 7, kk = idx & 127;
    int u = up & 63;
    int vfreq = (u + 32) & 63;
    int h = kk & 63;
    int r = (vfreq * h) & 63;
    float cv, sv;
    __sincosf((float)(PI2 / 64.0) * (float)r, &sv, &cv);
    float val;
    if (up < 64) val = (kk < 64) ? cv : sv;
    else         val = (kk < 64) ? -sv : cv;
    Ub[idx] = __float2bfloat16(val);
  }
}

// ---------------- weight fp32 -> bf16, K-padded (B^T layout) ----------------
__global__ __launch_bounds__(256) void wconv_kernel(
    const float* __restrict__ W, __hip_bfloat16* __restrict__ wB,
    int N, int Kd, int Kp) {
  int total = N * Kp;
  for (int idx = blockIdx.x * 256 + threadIdx.x; idx < total; idx += gridDim.x * 256) {
    int e = idx / Kp;
    int f = idx - e * Kp;
    float v = (f < Kd) ? W[(size_t)e * Kd + f] : 0.0f;
    wB[idx] = __float2bfloat16(v);
  }
}

// ---------------- fused MFMA rfft2 + fftshift + gather: 2 waves = 1 image ----------------
// R5 chassis (verified): wave pair (wp=0/1) splits stage 1 by X-row half and
// stage 2 by u' half. Phase E now stores DIRECTLY to global feats (same value,
// same element as R5's featbuf+copy — provably equivalent), deleting featbuf,
// bar3 and the copy loop. Per-image LDS: Xbf(8192)/Sout(8704) union = 8704.
// Block = 2 images + post(4608) = 22016 B -> 7 blocks/CU.
#define IMGB 8704
#define POSTB 4608

__global__ __launch_bounds__(256, 4) void fft_mfma_kernel(
    const float* __restrict__ x,
    const __hip_bfloat16* __restrict__ Tt,     // [80][64]
    const __hip_bfloat16* __restrict__ Ub,     // [128][128]
    const unsigned short* __restrict__ post16, // [64][36]
    __hip_bfloat16* __restrict__ feats,
    int K, int Kp) {
  __shared__ __align__(16) char lds[2 * IMGB + POSTB];
  const int tid = threadIdx.x;
  const int lane = tid & 63;
  const int w = tid >> 6;      // 0..3
  const int wi = w >> 1;       // image slot in block
  const int wp = w & 1;        // half index within image
  const int l4 = lane & 15;
  const int q = lane >> 4;
  const int img = blockIdx.x * 2 + wi;
  const int sp = img / 3;
  const int c = img - sp * 3;
  char* ibuf = lds + wi * IMGB;                       // Xbf/Sout union [0,8704)
  unsigned short* postl = (unsigned short*)(lds + 2 * IMGB);

  // ---- phase A: stage 8 float4 rows (wp*32..+32) in regs, then cvt + swizzled ds_write
  const float* xi = x + (size_t)img * 4096;
  float4 st[8];
  #pragma unroll
  for (int r = 0; r < 8; ++r) {
    int row = wp * 32 + r * 4 + q;
    st[r] = *reinterpret_cast<const float4*>(xi + row * 64 + l4 * 4);
  }
  // co-op: post table -> LDS (1152 dwords over 256 threads)
  {
    const unsigned int* src = reinterpret_cast<const unsigned int*>(post16);
    unsigned int* dst = reinterpret_cast<unsigned int*>(postl);
    for (int i = tid; i < 1152; i += 256) dst[i] = src[i];
  }
  #pragma unroll
  for (int r = 0; r < 8; ++r) {
    int row = wp * 32 + r * 4 + q;
    int off = row * 128 + (((l4 >> 1) ^ (row & 7)) * 16 + (l4 & 1) * 8);
    ushort4 b;
    b.x = f2b(st[r].x); b.y = f2b(st[r].y); b.z = f2b(st[r].z); b.w = f2b(st[r].w);
    *reinterpret_cast<ushort4*>(ibuf + off) = b;
  }

  // ---- phase B: stage 1 MFMA  S[wp half][80] = X * Tt^T   (20 MFMA/wave)
  f32x4 acc1[2][5] = {};
  #pragma unroll
  for (int ks = 0; ks < 2; ++ks) {
    bf16x8 a1[2], b1[5];
    #pragma unroll
    for (int am = 0; am < 2; ++am) {
      int h = (wp * 2 + am) * 16 + l4;
      int kg = ks * 4 + q;
      a1[am] = *reinterpret_cast<const bf16x8*>(ibuf + h * 128 + ((kg ^ (h & 7)) * 16));
    }
    #pragma unroll
    for (int n = 0; n < 5; ++n) {
      int row = n * 16 + l4;
      b1[n] = *reinterpret_cast<const bf16x8*>(
          (const char*)Tt + row * 128 + ks * 64 + q * 16);
    }
    #pragma unroll
    for (int am = 0; am < 2; ++am)
      #pragma unroll
      for (int n = 0; n < 5; ++n)
        acc1[am][n] = __builtin_amdgcn_mfma_f32_16x16x32_bf16(a1[am], b1[n], acc1[am][n], 0, 0, 0);
  }

  __syncthreads();   // bar1: both waves done reading Xbf (Sout overlays it); post visible

  // ---- phase C: write Sout[j<33][kk] (Re kk=h, Im kk=64+h), XOR-swizzled
  #pragma unroll
  for (int n = 0; n < 5; ++n) {
    int col = n * 16 + l4;
    bool isRe = (col < 33);
    bool isIm = (col >= 40 && col < 73);
    if (!(isRe || isIm)) continue;
    int j = isRe ? col : (col - 40);
    #pragma unroll
    for (int am = 0; am < 2; ++am) {
      int h0 = (wp * 2 + am) * 16 + q * 4;          // kk&7 stays in one 8-group
      int kk0 = isRe ? h0 : (h0 + 64);
      int off = j * 256 + (((kk0 >> 3) ^ (j & 15)) * 16 + (kk0 & 7) * 2);
      ushort4 b;
      b.x = f2b(acc1[am][n][0]); b.y = f2b(acc1[am][n][1]);
      b.z = f2b(acc1[am][n][2]); b.w = f2b(acc1[am][n][3]);
      *reinterpret_cast<ushort4*>(ibuf + off) = b;
    }
  }

  __syncthreads();   // bar2: Sout complete (both halves of kk)

  // ---- phase D: stage 2 MFMA  C2[48][u' half] = Sout * Ub^T   (48 MFMA/wave)
  // A-rows >33 clamped to row 33 (outputs discarded; matmul rows independent)
  f32x4 acc2[3][4] = {};
  #pragma unroll
  for (int ks = 0; ks < 4; ++ks) {
    bf16x8 a2[3], b2[4];
    #pragma unroll
    for (int m = 0; m < 3; ++m) {
      int j = m * 16 + l4;
      if (j > 33) j = 33;
      int kg = ks * 4 + q;
      a2[m] = *reinterpret_cast<const bf16x8*>(ibuf + j * 256 + ((kg ^ (j & 15)) * 16));
    }
    #pragma unroll
    for (int n = 0; n < 4; ++n) {
      int rowg = (wp * 4 + n) * 16 + l4;
      b2[n] = *reinterpret_cast<const bf16x8*>(
          (const char*)Ub + rowg * 256 + ks * 64 + q * 16);
    }
    #pragma unroll
    for (int m = 0; m < 3; ++m)
      #pragma unroll
      for (int n = 0; n < 4; ++n)
        acc2[m][n] = __builtin_amdgcn_mfma_f32_16x16x32_bf16(a2[m], b2[n], acc2[m][n], 0, 0, 0);
  }

  // ---- phase E: masked gather -> DIRECT global stores (wave 0: Re, wave 1: Im)
  {
    unsigned short* gOut = (unsigned short*)feats
        + (size_t)sp * Kp + (wp ? (size_t)3 * K : (size_t)0) + (size_t)c * K;
    #pragma unroll
    for (int n = 0; n < 4; ++n) {
      int u = n * 16 + l4;        // u' = wp*64 + u ; u is the H-frequency row
      #pragma unroll
      for (int m = 0; m < 3; ++m) {
        int j0 = m * 16 + q * 4;
        if (j0 > 32) continue;
        ushort4 kv = *reinterpret_cast<const ushort4*>(postl + u * 36 + j0);
        #pragma unroll
        for (int r = 0; r < 4; ++r) {
          int j = j0 + r;
          unsigned short k = (&kv.x)[r];
          if (j < 33 && k != 0xFFFFu)
            gOut[k] = f2b(acc2[m][n][r]);
        }
      }
    }
    if (wp == 0 && c == 2) {
      unsigned int* gp = reinterpret_cast<unsigned int*>(feats + (size_t)sp * Kp + (size_t)6 * K);
      int padDw = (Kp - 6 * K) / 2;
      if (lane < padDw) gp[lane] = 0u;
    }
  }
}

// ---------------- bf16 MFMA GEMM: out[M][N] = A[M][Kp] * B[N][Kp]^T + bias ----------------
#define BM 128
#define BN 128
#define BKK 64

__global__ __launch_bounds__(256) void gemm_bias_kernel(
    const __hip_bfloat16* __restrict__ A, const __hip_bfloat16* __restrict__ B,
    const float* __restrict__ bias, float* __restrict__ C,
    int M, int N, int Kp) {
  __shared__ __align__(16) unsigned short As[BM * BKK];
  __shared__ __align__(16) unsigned short Bs[BN * BKK];

  const int tid = threadIdx.x;
  const int lane = tid & 63;
  const int wid = tid >> 6;
  const int wm = wid & 1;
  const int wn = wid >> 1;
  const int nbm = M / BM;
  const int bm = blockIdx.x % nbm;
  const int bn = blockIdx.x / nbm;
  const int row0A = bm * BM;
  const int row0B = bn * BN;

  f32x4 acc[4][4] = {};

  for (int k0 = 0; k0 < Kp; k0 += BKK) {
    #pragma unroll
    for (int i = 0; i < 4; ++i) {
      int qc = i * 256 + tid;
      int r = qc >> 3;
      int cb = (qc & 7) * 16;
      const char* gA = (const char*)A + ((size_t)(row0A + r) * Kp + k0) * 2 + cb;
      const char* gB = (const char*)B + ((size_t)(row0B + r) * Kp + k0) * 2 + cb;
      char* lA = (char*)As + (size_t)(i * 256 + wid * 64) * 16;
      char* lB = (char*)Bs + (size_t)(i * 256 + wid * 64) * 16;
      __builtin_amdgcn_global_load_lds((const __attribute__((address_space(1))) void*)gA,
                                       (__attribute__((address_space(3))) void*)lA, 16, 0, 0);
      __builtin_amdgcn_global_load_lds((const __attribute__((address_space(1))) void*)gB,
                                       (__attribute__((address_space(3))) void*)lB, 16, 0, 0);
    }
    __syncthreads();

    #pragma unroll
    for (int kk = 0; kk < 2; ++kk) {
      bf16x8 afr[4], bfr[4];
      const int ke = kk * 32 + (lane >> 4) * 8;
      #pragma unroll
      for (int m = 0; m < 4; ++m) {
        int rowA = wm * 64 + m * 16 + (lane & 15);
        afr[m] = *reinterpret_cast<const bf16x8*>(&As[rowA * BKK + ke]);
      }
      #pragma unroll
      for (int n = 0; n < 4; ++n) {
        int rowB = wn * 64 + n * 16 + (lane & 15);
        bfr[n] = *reinterpret_cast<const bf16x8*>(&Bs[rowB * BKK + ke]);
      }
      #pragma unroll
      for (int m = 0; m < 4; ++m)
        #pragma unroll
        for (int n = 0; n < 4; ++n)
          acc[m][n] = __builtin_amdgcn_mfma_f32_16x16x32_bf16(afr[m], bfr[n], acc[m][n], 0, 0, 0);
    }
    __syncthreads();
  }

  #pragma unroll
  for (int n = 0; n < 4; ++n) {
    int gcol = row0B + wn * 64 + n * 16 + (lane & 15);
    float bv = bias[gcol];
    #pragma unroll
    for (int m = 0; m < 4; ++m) {
      int grow0 = row0A + wm * 64 + m * 16 + (lane >> 4) * 4;
      #pragma unroll
      for (int r = 0; r < 4; ++r) {
        C[(size_t)(grow0 + r) * N + gcol] = acc[m][n][r] + bv;
      }
    }
  }
}

extern "C" void kernel_launch(void* const* d_in, const int* in_sizes, int n_in,
                              void* d_out, int out_size, void* d_ws, size_t ws_size,
                              hipStream_t stream) {
  const float* x = (const float*)d_in[0];
  const float* W = (const float*)d_in[2];
  const float* bias = (const float*)d_in[3];
  float* out = (float*)d_out;

  const int ENC = in_sizes[3];                 // 1024
  const int Kd = in_sizes[2] / ENC;            // 6*K = 3252
  const int K = Kd / 6;                        // 542
  const int NIMG = in_sizes[0] / 4096;         // 12288
  const int SP = NIMG / 3;                     // 4096
  const int Kp = (Kd + 63) & ~63;              // 3264

  char* ws = (char*)d_ws;
  unsigned short* post16 = (unsigned short*)ws;            // 4608 (region 9216)
  __hip_bfloat16* Tt = (__hip_bfloat16*)(ws + 9216);       // 80*64*2 = 10240
  __hip_bfloat16* Ub = (__hip_bfloat16*)(ws + 19456);      // 128*128*2 = 32768
  __hip_bfloat16* wB = (__hip_bfloat16*)(ws + 52224);      // ENC*Kp*2
  size_t wBytes = (size_t)ENC * Kp * 2;
  __hip_bfloat16* feats = (__hip_bfloat16*)(ws + 52224 + wBytes);

  setup_tables_kernel<<<1, 256, 0, stream>>>(post16, Tt, Ub);
  wconv_kernel<<<1024, 256, 0, stream>>>(W, wB, ENC, Kd, Kp);
  fft_mfma_kernel<<<NIMG / 2, 256, 0, stream>>>(x, Tt, Ub, post16, feats, K, Kp);
  gemm_bias_kernel<<<(SP / BM) * (ENC / BN), 256, 0, stream>>>(feats, wB, bias, out, SP, ENC, Kp);
}